// Round 10
// baseline (1573.865 us; speedup 1.0000x reference)
//
#include <hip/hip_runtime.h>

typedef unsigned int u32;
typedef unsigned short u16;
typedef _Float16 f16;
typedef f16 f16x8 __attribute__((ext_vector_type(8)));
typedef float f32x4 __attribute__((ext_vector_type(4)));
typedef u16 u16x8 __attribute__((ext_vector_type(8)));

#define DIM 1024
#define BATCH 32768
#define RANK 32
#define NLIN 18

__device__ __forceinline__ u16 f2h(float f) {
    f16 h = (f16)f;
    return *(u16*)&h;
}
__device__ __forceinline__ float h2f(u16 u) {
    f16 h;
    *(u16*)&h = u;
    return (float)h;
}

__device__ __forceinline__ void gload16(const u16* g, u16* l) {
    __builtin_amdgcn_global_load_lds((__attribute__((address_space(1))) const void*)g,
                                     (__attribute__((address_space(3))) void*)l,
                                     16, 0, 0);
}

#define BAR()        __builtin_amdgcn_s_barrier()
#define SB0()        __builtin_amdgcn_sched_barrier(0)
#define ASM_VM0()    asm volatile("s_waitcnt vmcnt(0)" ::: "memory")
#define ASM_VM6()    asm volatile("s_waitcnt vmcnt(6)" ::: "memory")
#define ASM_VM8()    asm volatile("s_waitcnt vmcnt(8)" ::: "memory")
#define ASM_LG0()    asm volatile("s_waitcnt lgkmcnt(0)" ::: "memory")
#define ASM_LG4()    asm volatile("s_waitcnt lgkmcnt(4)" ::: "memory")

// ---- W_eff = dequant(wq, scales) + lb @ la  -> fp16 [NLIN][DIM][DIM] ----
__global__ __launch_bounds__(256) void build_weff(
    const int* __restrict__ wq, const float* __restrict__ scales,
    const float* __restrict__ la, const float* __restrict__ lb,
    u16* __restrict__ weff)
{
    const int rb = blockIdx.x;   // 0..63, 16 rows each
    const int li = blockIdx.y;   // 0..17
    const int tid = threadIdx.x;
    const int row0 = rb * 16;
    const int* wqL = wq + (size_t)li * DIM * DIM;
    const float* sL = scales + (size_t)li * (DIM * DIM / 16);
    const float* laL = la + (size_t)li * RANK * DIM;
    const float* lbL = lb + (size_t)li * DIM * RANK;
    u16* wout = weff + (size_t)li * DIM * DIM;

    for (int kc = 0; kc < 4; ++kc) {
        const int k = kc * 256 + tid;
        float lar[RANK];
        #pragma unroll
        for (int r = 0; r < RANK; ++r) lar[r] = laL[r * DIM + k];
        const int ks = k >> 4;
        #pragma unroll
        for (int og = 0; og < 16; og += 4) {
            const int m0 = row0 + og;
            float a0 = ((float)wqL[(m0 + 0) * DIM + k] - 8.0f) * sL[((m0 + 0) << 6) + ks];
            float a1 = ((float)wqL[(m0 + 1) * DIM + k] - 8.0f) * sL[((m0 + 1) << 6) + ks];
            float a2 = ((float)wqL[(m0 + 2) * DIM + k] - 8.0f) * sL[((m0 + 2) << 6) + ks];
            float a3 = ((float)wqL[(m0 + 3) * DIM + k] - 8.0f) * sL[((m0 + 3) << 6) + ks];
            #pragma unroll
            for (int r = 0; r < RANK; ++r) {
                const float lv = lar[r];
                a0 += lbL[(m0 + 0) * RANK + r] * lv;
                a1 += lbL[(m0 + 1) * RANK + r] * lv;
                a2 += lbL[(m0 + 2) * RANK + r] * lv;
                a3 += lbL[(m0 + 3) * RANK + r] * lv;
            }
            wout[(m0 + 0) * DIM + k] = f2h(a0);
            wout[(m0 + 1) * DIM + k] = f2h(a1);
            wout[(m0 + 2) * DIM + k] = f2h(a2);
            wout[(m0 + 3) * DIM + k] = f2h(a3);
        }
    }
}

// ---- x fp32 -> fp16 ----
__global__ __launch_bounds__(256) void xcast(const float* __restrict__ x, u16* __restrict__ o) {
    size_t i = ((size_t)blockIdx.x * 256 + threadIdx.x) * 8;
    float4 a = *(const float4*)(x + i);
    float4 b = *(const float4*)(x + i + 4);
    u16x8 v;
    v[0] = f2h(a.x); v[1] = f2h(a.y); v[2] = f2h(a.z); v[3] = f2h(a.w);
    v[4] = f2h(b.x); v[5] = f2h(b.y); v[6] = f2h(b.z); v[7] = f2h(b.w);
    *(u16x8*)(o + i) = v;
}

// ---- 256x256x(BK=64) GEMM, 8 waves (2Mx4N), 4 SUB-PHASES/K-tile.
// Sub-phase: {stage gloads; [counted vm]; BAR; counted lgkm; setprio+16 MFMA;
// post-MFMA ds_reads for a LATER sub-phase; SB0; BAR}. Single af/bf sets;
// every RD that overwrites a frag set is issued AFTER the QUAD consuming the
// old value (round-9 bug: sp3 read before QUAD(1,1) -> wrong operand. FIXED).
// Read placement: bf23(t)@sp0-pre, af_h1(t)@sp1-post, af_h0/bf01(t+1)@sp3-post.
// Staging regions race-free (A 3-buf: sp0/sp1; B 2-buf: sp2/sp3; each >=2
// barriers past all waves' drain of that region). One VM6/tile @sp2 retires
// exactly t+1's 8 loads (ages 4-6 sub-phases), leaves t+2's 6 in flight.
// LDS = 96K A + 64K B = 160 KiB. Zero-conflict chunk-XOR swizzle.
// EPI: 0 = relu(acc+bias)->fp16 ; 1 = acc+bias+res->fp16 ; 2 = acc+bias+res->fp32
template<int EPI>
__global__ __launch_bounds__(512, 2) void gemm256(
    const u16* __restrict__ X, const u16* __restrict__ W,
    const float* __restrict__ bias, const u16* __restrict__ res,
    void* __restrict__ outp)
{
    __shared__ __align__(16) u16 As3[3 * 16384];
    __shared__ __align__(16) u16 Bs[2 * 16384];
    const int tid = threadIdx.x;
    const int bid = blockIdx.x;
    // XCD-bijective swizzle: 512 blocks, 8 XCDs, 64 contiguous wg per XCD
    const int wg = (bid & 7) * 64 + (bid >> 3);
    const int bm = wg >> 2;        // 0..127
    const int bn = wg & 3;         // 0..3
    const int wid = tid >> 6;
    const int lane = tid & 63;
    const int wm = wid >> 2;       // 0..1
    const int wn = wid & 3;        // 0..3

    // ---- staging source pointers (global side carries the swizzle) ----
    const int c1 = tid, c2 = tid + 512;           // chunk ids within a 1024-chunk half
    const int r1 = c1 >> 3, r2 = c2 >> 3;         // rows 0..127 within half
    const int l1 = ((c1 & 7) ^ (r1 & 7)) * 8;     // swizzled k-offset (u16)
    const int l2 = ((c2 & 7) ^ (r2 & 7)) * 8;
    const u16* gA0a = X + (size_t)(bm * 256 +       r1) * DIM + l1;
    const u16* gA0b = X + (size_t)(bm * 256 +       r2) * DIM + l2;
    const u16* gA1a = X + (size_t)(bm * 256 + 128 + r1) * DIM + l1;
    const u16* gA1b = X + (size_t)(bm * 256 + 128 + r2) * DIM + l2;
    const u16* gB0a = W + (size_t)(bn * 256 +       r1) * DIM + l1;
    const u16* gB0b = W + (size_t)(bn * 256 +       r2) * DIM + l2;
    const u16* gB1a = W + (size_t)(bn * 256 + 128 + r1) * DIM + l1;
    const u16* gB1b = W + (size_t)(bn * 256 + 128 + r2) * DIM + l2;
    const int d1 = c1 * 8, d2 = c2 * 8;           // linear LDS dest (u16), half adds 8192

    // ---- fragment read offsets ----
    const int kg = lane >> 4;
    const int sw = lane & 7;
    const int ch0 = ((0 * 4 + kg) ^ sw) * 8;      // ks=0 chunk (u16 offset in row)
    const int ch1 = ((1 * 4 + kg) ^ sw) * 8;      // ks=1
    const int aoff = (wm * 128 + (lane & 15)) * 64;
    const int boff = (wn * 64 + (lane & 15)) * 64;

    f32x4 acc[8][4];
    #pragma unroll
    for (int i = 0; i < 8; ++i)
        #pragma unroll
        for (int j = 0; j < 4; ++j)
            acc[i][j] = (f32x4){0.f, 0.f, 0.f, 0.f};
    f16x8 af[4][2];   // A fragments (one half at a time)
    f16x8 bf[4][2];   // B fragments (bf[0:1]=cols 0-31, bf[2:3]=cols 32-63)

    #define RD_A(MH, BUF) { \
        _Pragma("unroll") \
        for (int fm = 0; fm < 4; ++fm) { \
            af[fm][0] = *(const f16x8*)&(BUF)[aoff + ((MH)*64 + fm*16)*64 + ch0]; \
            af[fm][1] = *(const f16x8*)&(BUF)[aoff + ((MH)*64 + fm*16)*64 + ch1]; \
        } }
    #define RD_B01(BUF) { \
        _Pragma("unroll") \
        for (int fn = 0; fn < 2; ++fn) { \
            bf[fn][0] = *(const f16x8*)&(BUF)[boff + (fn*16)*64 + ch0]; \
            bf[fn][1] = *(const f16x8*)&(BUF)[boff + (fn*16)*64 + ch1]; \
        } }
    #define RD_B23(BUF) { \
        _Pragma("unroll") \
        for (int fn = 2; fn < 4; ++fn) { \
            bf[fn][0] = *(const f16x8*)&(BUF)[boff + (fn*16)*64 + ch0]; \
            bf[fn][1] = *(const f16x8*)&(BUF)[boff + (fn*16)*64 + ch1]; \
        } }
    #define QUAD(MH, NH) { \
        __builtin_amdgcn_s_setprio(1); \
        _Pragma("unroll") \
        for (int ks = 0; ks < 2; ++ks) \
            _Pragma("unroll") \
            for (int fm = 0; fm < 4; ++fm) \
                _Pragma("unroll") \
                for (int fn = 0; fn < 2; ++fn) \
                    acc[(MH)*4+fm][(NH)*2+fn] = __builtin_amdgcn_mfma_f32_16x16x32_f16( \
                        af[fm][ks], bf[(NH)*2+fn][ks], acc[(MH)*4+fm][(NH)*2+fn], 0, 0, 0); \
        __builtin_amdgcn_s_setprio(0); }

    // ---- prologue: stage t0 [Ah0,Ah1,Bh0,Bh1], then t1 same order ----
    gload16(gA0a, &As3[d1]);        gload16(gA0b, &As3[d2]);
    gload16(gA1a, &As3[8192 + d1]); gload16(gA1b, &As3[8192 + d2]);
    gload16(gB0a, &Bs[d1]);         gload16(gB0b, &Bs[d2]);
    gload16(gB1a, &Bs[8192 + d1]);  gload16(gB1b, &Bs[8192 + d2]);
    gload16(gA0a + 64, &As3[16384 + d1]);        gload16(gA0b + 64, &As3[16384 + d2]);
    gload16(gA1a + 64, &As3[16384 + 8192 + d1]); gload16(gA1b + 64, &As3[16384 + 8192 + d2]);
    gload16(gB0a + 64, &Bs[16384 + d1]);         gload16(gB0b + 64, &Bs[16384 + d2]);
    gload16(gB1a + 64, &Bs[16384 + 8192 + d1]);  gload16(gB1b + 64, &Bs[16384 + 8192 + d2]);

    ASM_VM8();     // t0's 8 loads landed (t1's 8 stay in flight)
    BAR();
    // emulate sp3(-1): pre-read af_h0(0) + bf01(0)
    RD_A(0, (&As3[0]));
    RD_B01((&Bs[0]));
    SB0();

    int aCur = 0, aNext = 16384, aWr = 32768;
    int bCur = 0, bNext = 16384;
    #pragma unroll 1
    for (int t = 0; t < 16; ++t) {
        const int ko2 = (t + 2) * 64;
        const bool st = (t <= 13);
        // ---- sp0: QUAD(0,0) [af_h0 x bf01] ----
        RD_B23((&Bs[bCur]));                       // for sp1 (bf23 WAR-free: old bf23 consumed @sp3(t-1))
        if (st) { gload16(gA0a + ko2, &As3[aWr + d1]); gload16(gA0b + ko2, &As3[aWr + d2]); }
        SB0();
        BAR();
        ASM_LG4();                                 // af_h0+bf01 done; bf23 in flight
        QUAD(0, 0);
        SB0();
        BAR();
        // ---- sp1: QUAD(0,1) [af_h0 x bf23] ----
        if (st) { gload16(gA1a + ko2, &As3[aWr + 8192 + d1]); gload16(gA1b + ko2, &As3[aWr + 8192 + d2]); }
        SB0();
        BAR();
        ASM_LG0();                                 // bf23 done
        QUAD(0, 1);
        RD_A(1, (&As3[aCur]));                     // af <- Ah1(t), AFTER its consumers
        SB0();
        BAR();
        // ---- sp2: QUAD(1,0) [af_h1 x bf01] ----
        if (st) { gload16(gB0a + ko2, &Bs[bCur + d1]); gload16(gB0b + ko2, &Bs[bCur + d2]); }
        if (st) ASM_VM6(); else if (t == 14) ASM_VM0();   // retire all t+1 staging
        SB0();
        BAR();
        ASM_LG0();                                 // af_h1 done
        QUAD(1, 0);
        SB0();
        BAR();
        // ---- sp3: QUAD(1,1) [af_h1 x bf23] (deps drained @sp2/sp1) ----
        if (st) { gload16(gB1a + ko2, &Bs[bCur + 8192 + d1]); gload16(gB1b + ko2, &Bs[bCur + 8192 + d2]); }
        SB0();
        BAR();
        QUAD(1, 1);
        if (t <= 14) {                             // reads AFTER QUAD(1,1) — t+1 frags
            RD_A(0, (&As3[aNext]));                // (visible: VM6+BAR @sp2)
            RD_B01((&Bs[bNext]));
        }
        SB0();
        BAR();
        int tmp = aCur; aCur = aNext; aNext = aWr; aWr = tmp;
        tmp = bCur; bCur = bNext; bNext = tmp;
    }

    // ---- epilogue: LDS transpose -> full-line vector stores ----
    ASM_LG0();
    float* blk = (float*)&As3[0] + wid * 1088;   // [16][68] f32 per wave
    const int mrow = bm * 256 + wm * 128;
    const int ncol = bn * 256 + wn * 64 + (lane & 7) * 8;
    float4 bv0 = *(const float4*)&bias[ncol];
    float4 bv1 = *(const float4*)&bias[ncol + 4];
    #pragma unroll
    for (int fm = 0; fm < 8; ++fm) {
        __builtin_amdgcn_sched_barrier(0);
        #pragma unroll
        for (int fn = 0; fn < 4; ++fn)
            #pragma unroll
            for (int reg = 0; reg < 4; ++reg)
                blk[((lane >> 4) * 4 + reg) * 68 + (lane & 15) + fn * 16] = acc[fm][fn][reg];
        ASM_LG0();
        __builtin_amdgcn_sched_barrier(0);
        #pragma unroll
        for (int pass = 0; pass < 2; ++pass) {
            const float* rp = &blk[(pass * 8 + (lane >> 3)) * 68 + (lane & 7) * 8];
            float4 v0 = *(const float4*)rp;
            float4 v1 = *(const float4*)(rp + 4);
            v0.x += bv0.x; v0.y += bv0.y; v0.z += bv0.z; v0.w += bv0.w;
            v1.x += bv1.x; v1.y += bv1.y; v1.z += bv1.z; v1.w += bv1.w;
            const int m = mrow + fm * 16 + pass * 8 + (lane >> 3);
            const size_t gi = (size_t)m * DIM + ncol;
            if (EPI == 0) {
                u16x8 o;
                o[0] = f2h(fmaxf(v0.x, 0.f)); o[1] = f2h(fmaxf(v0.y, 0.f));
                o[2] = f2h(fmaxf(v0.z, 0.f)); o[3] = f2h(fmaxf(v0.w, 0.f));
                o[4] = f2h(fmaxf(v1.x, 0.f)); o[5] = f2h(fmaxf(v1.y, 0.f));
                o[6] = f2h(fmaxf(v1.z, 0.f)); o[7] = f2h(fmaxf(v1.w, 0.f));
                *(u16x8*)((u16*)outp + gi) = o;
            } else {
                u16x8 rv = *(const u16x8*)(res + gi);
                v0.x += h2f(rv[0]); v0.y += h2f(rv[1]); v0.z += h2f(rv[2]); v0.w += h2f(rv[3]);
                v1.x += h2f(rv[4]); v1.y += h2f(rv[5]); v1.z += h2f(rv[6]); v1.w += h2f(rv[7]);
                if (EPI == 1) {
                    u16x8 o;
                    o[0] = f2h(v0.x); o[1] = f2h(v0.y); o[2] = f2h(v0.z); o[3] = f2h(v0.w);
                    o[4] = f2h(v1.x); o[5] = f2h(v1.y); o[6] = f2h(v1.z); o[7] = f2h(v1.w);
                    *(u16x8*)((u16*)outp + gi) = o;
                } else {
                    *(float4*)((float*)outp + gi) = v0;
                    *(float4*)((float*)outp + gi + 4) = v1;
                }
            }
        }
        ASM_LG0();
    }
    #undef RD_A
    #undef RD_B01
    #undef RD_B23
    #undef QUAD
}

// ---- LayerNorm: fp16 in -> fp16 out, one wave per row ----
__global__ __launch_bounds__(256) void ln_k(const u16* __restrict__ in,
    const float* __restrict__ g, const float* __restrict__ b, u16* __restrict__ out)
{
    int row = blockIdx.x * 4 + (threadIdx.x >> 6);
    int lane = threadIdx.x & 63;
    const u16* rp = in + (size_t)row * DIM;
    u16x8 v0 = *(const u16x8*)(rp + lane * 8);
    u16x8 v1 = *(const u16x8*)(rp + 512 + lane * 8);
    float f[16];
    #pragma unroll
    for (int j = 0; j < 8; ++j) { f[j] = h2f(v0[j]); f[8 + j] = h2f(v1[j]); }
    float s = 0.f, sq = 0.f;
    #pragma unroll
    for (int j = 0; j < 16; ++j) { s += f[j]; sq += f[j] * f[j]; }
    #pragma unroll
    for (int m = 1; m < 64; m <<= 1) { s += __shfl_xor(s, m); sq += __shfl_xor(sq, m); }
    float mean = s * (1.0f / 1024.0f);
    float var = sq * (1.0f / 1024.0f) - mean * mean;
    float rstd = 1.0f / sqrtf(var + 1e-5f);
    u16x8 o0, o1;
    #pragma unroll
    for (int j = 0; j < 8; ++j) {
        int c0 = lane * 8 + j, c1 = 512 + lane * 8 + j;
        o0[j] = f2h((f[j] - mean) * rstd * g[c0] + b[c0]);
        o1[j] = f2h((f[8 + j] - mean) * rstd * g[c1] + b[c1]);
    }
    u16* op = out + (size_t)row * DIM;
    *(u16x8*)(op + lane * 8) = o0;
    *(u16x8*)(op + 512 + lane * 8) = o1;
}

extern "C" void kernel_launch(void* const* d_in, const int* in_sizes, int n_in,
                              void* d_out, int out_size, void* d_ws, size_t ws_size,
                              hipStream_t stream) {
    const float* x      = (const float*)d_in[0];
    const int*   wq     = (const int*)d_in[1];
    const float* scales = (const float*)d_in[2];
    const float* bias   = (const float*)d_in[3];
    const float* la     = (const float*)d_in[4];
    const float* lb     = (const float*)d_in[5];
    const float* gamma  = (const float*)d_in[6];
    const float* beta   = (const float*)d_in[7];

    char* ws = (char*)d_ws;
    u16* Weff = (u16*)ws;                                      // 37,748,736 B
    u16* actA = (u16*)(ws + (size_t)NLIN * DIM * DIM * 2);     // 67,108,864 B
    u16* actB = actA + (size_t)BATCH * DIM;                    // 67,108,864 B
    u16* dob  = (u16*)d_out;   // d_out doubles as fp16 scratch (134 MB total)
    float* dof = (float*)d_out;

    build_weff<<<dim3(64, 18), 256, 0, stream>>>(wq, scales, la, lb, Weff);
    xcast<<<(BATCH * DIM) / 2048, 256, 0, stream>>>(x, actA);

    int li = 0;
    for (int blk = 0; blk < 6; ++blk) {
        const u16* w0 = Weff + (size_t)(li + 0) * DIM * DIM;
        const u16* w1 = Weff + (size_t)(li + 1) * DIM * DIM;
        const u16* w2 = Weff + (size_t)(li + 2) * DIM * DIM;
        const float* b0 = bias + (li + 0) * DIM;
        const float* b1 = bias + (li + 1) * DIM;
        const float* b2 = bias + (li + 2) * DIM;
        if (blk < 5) {
            // X(actA) -> h1(actB) -> h2(d_out fp16) -> h3(actB) -> LN -> actA
            gemm256<0><<<512, 512, 0, stream>>>(actA, w0, b0, nullptr, actB);
            gemm256<0><<<512, 512, 0, stream>>>(actB, w1, b1, nullptr, dob);
            gemm256<1><<<512, 512, 0, stream>>>(dob,  w2, b2, actA, actB);
            ln_k<<<BATCH / 4, 256, 0, stream>>>(actB, gamma + blk * DIM, beta + blk * DIM, actA);
        } else {
            // final block: keep d_out free of live reads at the fp32 write
            gemm256<0><<<512, 512, 0, stream>>>(actA, w0, b0, nullptr, dob);
            gemm256<0><<<512, 512, 0, stream>>>(dob,  w1, b1, nullptr, actB);
            gemm256<2><<<512, 512, 0, stream>>>(actB, w2, b2, actA, (void*)dof);
        }
        li += 3;
    }
}

// Round 11
// 1497.138 us; speedup vs baseline: 1.0512x; 1.0512x over previous
//
#include <hip/hip_runtime.h>

typedef unsigned int u32;
typedef unsigned short u16;
typedef _Float16 f16;
typedef f16 f16x8 __attribute__((ext_vector_type(8)));
typedef float f32x4 __attribute__((ext_vector_type(4)));
typedef u16 u16x8 __attribute__((ext_vector_type(8)));

#define DIM 1024
#define BATCH 32768
#define RANK 32
#define NLIN 18

__device__ __forceinline__ u16 f2h(float f) {
    f16 h = (f16)f;
    return *(u16*)&h;
}
__device__ __forceinline__ float h2f(u16 u) {
    f16 h;
    *(u16*)&h = u;
    return (float)h;
}

__device__ __forceinline__ void gload16(const u16* g, u16* l) {
    __builtin_amdgcn_global_load_lds((__attribute__((address_space(1))) const void*)g,
                                     (__attribute__((address_space(3))) void*)l,
                                     16, 0, 0);
}

#define BAR()        __builtin_amdgcn_s_barrier()
#define SB0()        __builtin_amdgcn_sched_barrier(0)
#define ASM_VM0()    asm volatile("s_waitcnt vmcnt(0)" ::: "memory")
#define ASM_VM4()    asm volatile("s_waitcnt vmcnt(4)" ::: "memory")
#define ASM_VM8()    asm volatile("s_waitcnt vmcnt(8)" ::: "memory")
#define ASM_LG0()    asm volatile("s_waitcnt lgkmcnt(0)" ::: "memory")

// ---- W_eff = dequant(wq, scales) + lb @ la  -> fp16 [NLIN][DIM][DIM] ----
__global__ __launch_bounds__(256) void build_weff(
    const int* __restrict__ wq, const float* __restrict__ scales,
    const float* __restrict__ la, const float* __restrict__ lb,
    u16* __restrict__ weff)
{
    const int rb = blockIdx.x;   // 0..63, 16 rows each
    const int li = blockIdx.y;   // 0..17
    const int tid = threadIdx.x;
    const int row0 = rb * 16;
    const int* wqL = wq + (size_t)li * DIM * DIM;
    const float* sL = scales + (size_t)li * (DIM * DIM / 16);
    const float* laL = la + (size_t)li * RANK * DIM;
    const float* lbL = lb + (size_t)li * DIM * RANK;
    u16* wout = weff + (size_t)li * DIM * DIM;

    for (int kc = 0; kc < 4; ++kc) {
        const int k = kc * 256 + tid;
        float lar[RANK];
        #pragma unroll
        for (int r = 0; r < RANK; ++r) lar[r] = laL[r * DIM + k];
        const int ks = k >> 4;
        #pragma unroll
        for (int og = 0; og < 16; og += 4) {
            const int m0 = row0 + og;
            float a0 = ((float)wqL[(m0 + 0) * DIM + k] - 8.0f) * sL[((m0 + 0) << 6) + ks];
            float a1 = ((float)wqL[(m0 + 1) * DIM + k] - 8.0f) * sL[((m0 + 1) << 6) + ks];
            float a2 = ((float)wqL[(m0 + 2) * DIM + k] - 8.0f) * sL[((m0 + 2) << 6) + ks];
            float a3 = ((float)wqL[(m0 + 3) * DIM + k] - 8.0f) * sL[((m0 + 3) << 6) + ks];
            #pragma unroll
            for (int r = 0; r < RANK; ++r) {
                const float lv = lar[r];
                a0 += lbL[(m0 + 0) * RANK + r] * lv;
                a1 += lbL[(m0 + 1) * RANK + r] * lv;
                a2 += lbL[(m0 + 2) * RANK + r] * lv;
                a3 += lbL[(m0 + 3) * RANK + r] * lv;
            }
            wout[(m0 + 0) * DIM + k] = f2h(a0);
            wout[(m0 + 1) * DIM + k] = f2h(a1);
            wout[(m0 + 2) * DIM + k] = f2h(a2);
            wout[(m0 + 3) * DIM + k] = f2h(a3);
        }
    }
}

// ---- x fp32 -> fp16 ----
__global__ __launch_bounds__(256) void xcast(const float* __restrict__ x, u16* __restrict__ o) {
    size_t i = ((size_t)blockIdx.x * 256 + threadIdx.x) * 8;
    float4 a = *(const float4*)(x + i);
    float4 b = *(const float4*)(x + i + 4);
    u16x8 v;
    v[0] = f2h(a.x); v[1] = f2h(a.y); v[2] = f2h(a.z); v[3] = f2h(a.w);
    v[4] = f2h(b.x); v[5] = f2h(b.y); v[6] = f2h(b.z); v[7] = f2h(b.w);
    *(u16x8*)(o + i) = v;
}

// ---- 256x256x(BK=64) GEMM, 8 waves (2Mx4N), 2 phases/K-tile (round-8 loop,
// the best-measured schedule). Race-free staging: A triple-buffered (staged
// ph0, region drained by all waves at top-BAR of the PREVIOUS tile), B
// double-buffered (staged ph1, region drained at mid-BAR). One VM4 per tile
// at ph0-end drains t+1 fully; mid-BAR publishes. Pre-barrier fragment reads
// (single af/bf sets, issued AFTER their consumers' QUADs -> no reg growth).
// LDS = 96K A + 64K B = 160 KiB. Zero-conflict chunk-XOR swizzle.
// NEW epilogue (EPI 0/1): cross-wave LDS gather of fp16 results so each
// global store instruction covers 512B-contiguous -> full 256B HBM atoms
// (kills the 2x write amplification). EPI2 keeps fp32 scattered path.
template<int EPI>
__global__ __launch_bounds__(512, 2) void gemm256(
    const u16* __restrict__ X, const u16* __restrict__ W,
    const float* __restrict__ bias, const u16* __restrict__ res,
    void* __restrict__ outp)
{
    __shared__ __align__(16) u16 As3[3 * 16384];
    __shared__ __align__(16) u16 Bs[2 * 16384];
    const int tid = threadIdx.x;
    const int bid = blockIdx.x;
    // XCD-bijective swizzle: 512 blocks, 8 XCDs, 64 contiguous wg per XCD
    const int wg = (bid & 7) * 64 + (bid >> 3);
    const int bm = wg >> 2;        // 0..127
    const int bn = wg & 3;         // 0..3
    const int wid = tid >> 6;
    const int lane = tid & 63;
    const int wm = wid >> 2;       // 0..1
    const int wn = wid & 3;        // 0..3

    // ---- staging source pointers (global side carries the swizzle) ----
    const int c1 = tid, c2 = tid + 512;           // chunk ids within a 1024-chunk half
    const int r1 = c1 >> 3, r2 = c2 >> 3;         // rows 0..127 within half
    const int l1 = ((c1 & 7) ^ (r1 & 7)) * 8;     // swizzled k-offset (u16)
    const int l2 = ((c2 & 7) ^ (r2 & 7)) * 8;
    const u16* gA0a = X + (size_t)(bm * 256 +       r1) * DIM + l1;
    const u16* gA0b = X + (size_t)(bm * 256 +       r2) * DIM + l2;
    const u16* gA1a = X + (size_t)(bm * 256 + 128 + r1) * DIM + l1;
    const u16* gA1b = X + (size_t)(bm * 256 + 128 + r2) * DIM + l2;
    const u16* gB0a = W + (size_t)(bn * 256 +       r1) * DIM + l1;
    const u16* gB0b = W + (size_t)(bn * 256 +       r2) * DIM + l2;
    const u16* gB1a = W + (size_t)(bn * 256 + 128 + r1) * DIM + l1;
    const u16* gB1b = W + (size_t)(bn * 256 + 128 + r2) * DIM + l2;
    const int d1 = c1 * 8, d2 = c2 * 8;           // linear LDS dest (u16), half adds 8192

    // ---- fragment read offsets ----
    const int kg = lane >> 4;
    const int sw = lane & 7;
    const int ch0 = ((0 * 4 + kg) ^ sw) * 8;      // ks=0 chunk (u16 offset in row)
    const int ch1 = ((1 * 4 + kg) ^ sw) * 8;      // ks=1
    const int aoff = (wm * 128 + (lane & 15)) * 64;
    const int boff = (wn * 64 + (lane & 15)) * 64;

    f32x4 acc[8][4];
    #pragma unroll
    for (int i = 0; i < 8; ++i)
        #pragma unroll
        for (int j = 0; j < 4; ++j)
            acc[i][j] = (f32x4){0.f, 0.f, 0.f, 0.f};
    f16x8 af[4][2];   // A fragments (one half at a time)
    f16x8 bf[4][2];   // B fragments (all 64 cols of this wave)

    // ---- prologue: stage t0 (A,B), then t1 (B FIRST, then A) ----
    gload16(gA0a, &As3[d1]);        gload16(gA0b, &As3[d2]);
    gload16(gA1a, &As3[8192 + d1]); gload16(gA1b, &As3[8192 + d2]);
    gload16(gB0a, &Bs[d1]);         gload16(gB0b, &Bs[d2]);
    gload16(gB1a, &Bs[8192 + d1]);  gload16(gB1b, &Bs[8192 + d2]);
    gload16(gB0a + 64, &Bs[16384 + d1]);         gload16(gB0b + 64, &Bs[16384 + d2]);
    gload16(gB1a + 64, &Bs[16384 + 8192 + d1]);  gload16(gB1b + 64, &Bs[16384 + 8192 + d2]);
    gload16(gA0a + 64, &As3[16384 + d1]);        gload16(gA0b + 64, &As3[16384 + d2]);
    gload16(gA1a + 64, &As3[16384 + 8192 + d1]); gload16(gA1b + 64, &As3[16384 + 8192 + d2]);

    #define RD_A(MH, BUF) { \
        _Pragma("unroll") \
        for (int fm = 0; fm < 4; ++fm) { \
            af[fm][0] = *(const f16x8*)&(BUF)[aoff + ((MH)*64 + fm*16)*64 + ch0]; \
            af[fm][1] = *(const f16x8*)&(BUF)[aoff + ((MH)*64 + fm*16)*64 + ch1]; \
        } }
    #define RD_B(BUF) { \
        _Pragma("unroll") \
        for (int fn = 0; fn < 4; ++fn) { \
            bf[fn][0] = *(const f16x8*)&(BUF)[boff + (fn*16)*64 + ch0]; \
            bf[fn][1] = *(const f16x8*)&(BUF)[boff + (fn*16)*64 + ch1]; \
        } }
    #define QUAD(MH, NH) { \
        __builtin_amdgcn_s_setprio(1); \
        _Pragma("unroll") \
        for (int ks = 0; ks < 2; ++ks) \
            _Pragma("unroll") \
            for (int fm = 0; fm < 4; ++fm) \
                _Pragma("unroll") \
                for (int fn = 0; fn < 2; ++fn) \
                    acc[(MH)*4+fm][(NH)*2+fn] = __builtin_amdgcn_mfma_f32_16x16x32_f16( \
                        af[fm][ks], bf[(NH)*2+fn][ks], acc[(MH)*4+fm][(NH)*2+fn], 0, 0, 0); \
        __builtin_amdgcn_s_setprio(0); }

    ASM_VM8();     // t0's 8 loads landed (t1's 8 stay in flight)
    BAR();
    // pre-read tile0 fragments
    RD_A(0, (&As3[0]));
    RD_B((&Bs[0]));

    int aCur = 0, aNext = 16384, aWr = 32768;
    int bCur = 0, bNext = 16384;
    #pragma unroll 1
    for (int t = 0; t < 16; ++t) {
        const int ko2 = (t + 2) * 64;
        // ---- ph0 (post top-BAR: A(t-1) region globally drained) ----
        if (t <= 13) {   // stage A(t+2) -> As3[(t+2)%3]
            gload16(gA0a + ko2, &As3[aWr + d1]);        gload16(gA0b + ko2, &As3[aWr + d2]);
            gload16(gA1a + ko2, &As3[aWr + 8192 + d1]); gload16(gA1b + ko2, &As3[aWr + 8192 + d2]);
        }
        ASM_LG0(); SB0();
        QUAD(0, 0); QUAD(0, 1);        // af(h0,t), bf(t) — read pre-barrier
        RD_A(1, (&As3[aCur]));         // af <- A(t) h1, AFTER its consumers
        if (t <= 13) ASM_VM4(); else if (t == 14) ASM_VM0();
        BAR();
        // ---- ph1 (post mid-BAR: B(t) region globally drained) ----
        if (t <= 13) {   // stage B(t+2) -> Bs[t&1]
            gload16(gB0a + ko2, &Bs[bCur + d1]);        gload16(gB0b + ko2, &Bs[bCur + d2]);
            gload16(gB1a + ko2, &Bs[bCur + 8192 + d1]); gload16(gB1b + ko2, &Bs[bCur + 8192 + d2]);
        }
        ASM_LG0(); SB0();
        QUAD(1, 0); QUAD(1, 1);        // af(h1), bf
        if (t <= 14) {                 // pre-read tile t+1 (landed: VM4+mid-BAR)
            RD_A(0, (&As3[aNext]));
            RD_B((&Bs[bNext]));
        }
        BAR();                         // top-BAR
        int tmp = aCur; aCur = aNext; aNext = aWr; aWr = tmp;
        tmp = bCur; bCur = bNext; bNext = tmp;
    }

    // ---- epilogue ----
    ASM_LG0();
    const int mrow = bm * 256 + wm * 128;
    if (EPI == 2) {
        // fp32 path (1 of 18 dispatches): old per-wave transpose, fp32 stores
        BAR();
        float* blk = (float*)&As3[0] + wid * 1088;   // [16][68] f32 per wave
        const int ncol = bn * 256 + wn * 64 + (lane & 7) * 8;
        float4 bv0 = *(const float4*)&bias[ncol];
        float4 bv1 = *(const float4*)&bias[ncol + 4];
        #pragma unroll
        for (int fm = 0; fm < 8; ++fm) {
            __builtin_amdgcn_sched_barrier(0);
            #pragma unroll
            for (int fn = 0; fn < 4; ++fn)
                #pragma unroll
                for (int reg = 0; reg < 4; ++reg)
                    blk[((lane >> 4) * 4 + reg) * 68 + (lane & 15) + fn * 16] = acc[fm][fn][reg];
            ASM_LG0();
            __builtin_amdgcn_sched_barrier(0);
            #pragma unroll
            for (int pass = 0; pass < 2; ++pass) {
                const float* rp = &blk[(pass * 8 + (lane >> 3)) * 68 + (lane & 7) * 8];
                float4 v0 = *(const float4*)rp;
                float4 v1 = *(const float4*)(rp + 4);
                v0.x += bv0.x; v0.y += bv0.y; v0.z += bv0.z; v0.w += bv0.w;
                v1.x += bv1.x; v1.y += bv1.y; v1.z += bv1.z; v1.w += bv1.w;
                const int m = mrow + fm * 16 + pass * 8 + (lane >> 3);
                const size_t gi = (size_t)m * DIM + ncol;
                u16x8 rv = *(const u16x8*)(res + gi);
                v0.x += h2f(rv[0]); v0.y += h2f(rv[1]); v0.z += h2f(rv[2]); v0.w += h2f(rv[3]);
                v1.x += h2f(rv[4]); v1.y += h2f(rv[5]); v1.z += h2f(rv[6]); v1.w += h2f(rv[7]);
                *(float4*)((float*)outp + gi) = v0;
                *(float4*)((float*)outp + gi + 4) = v1;
            }
            ASM_LG0();
        }
    } else {
        // fp16 path: cross-wave gather -> 512B-contiguous stores (full 256B atoms)
        // Region per wm-half: [16 rows][264 u16] (256 cols + 8 pad), 8448 B.
        u16* half = &As3[0] + wm * 8448;
        const int colw = wn * 64 + (lane & 15);     // this thread's column set
        const int rquad = (lane >> 4) * 4;          // rows rquad..rquad+3 per reg
        // per-thread output columns for the store pass:
        const int srow8 = tid & 255;                // 0..255 within half
        const int orow = srow8 >> 5;                // 0..7 (x2 passes = 16 rows)
        const int ocol = (srow8 & 31) * 8;          // 0..248, 8 u16 = 16B per lane
        u16* hw = &As3[0] + (tid >> 8) * 8448;      // store-side half (tid>>8 == wm of this tid's gather role)
        const int gncol = bn * 256 + ocol;
        float bvc[4];
        #pragma unroll
        for (int fn = 0; fn < 4; ++fn) bvc[fn] = bias[bn * 256 + wn * 64 + (lane & 15) + fn * 16];
        #pragma unroll
        for (int fm = 0; fm < 8; ++fm) {
            BAR();   // region free: previous fm's reads done block-wide
            #pragma unroll
            for (int fn = 0; fn < 4; ++fn) {
                #pragma unroll
                for (int reg = 0; reg < 4; ++reg) {
                    float v = acc[fm][fn][reg] + bvc[fn];
                    if (EPI == 0) v = fmaxf(v, 0.0f);
                    else {
                        const int m = mrow + fm * 16 + rquad + reg;
                        v += h2f(res[(size_t)m * DIM + bn * 256 + colw + fn * 16]);
                    }
                    half[(rquad + reg) * 264 + colw + fn * 16] = f2h(v);
                }
            }
            ASM_LG0();
            BAR();   // all waves' fp16 results for this fm visible
            #pragma unroll
            for (int pass = 0; pass < 2; ++pass) {
                const int r = pass * 8 + orow;
                u16x8 o = *(const u16x8*)&hw[r * 264 + ocol];
                const int m = (tid >> 8) * 128 + bm * 256 + fm * 16 + r;
                *(u16x8*)((u16*)outp + (size_t)m * DIM + gncol) = o;
            }
            ASM_LG0();
        }
    }
    #undef RD_A
    #undef RD_B
    #undef QUAD
}

// ---- LayerNorm: fp16 in -> fp16 out, one wave per row ----
__global__ __launch_bounds__(256) void ln_k(const u16* __restrict__ in,
    const float* __restrict__ g, const float* __restrict__ b, u16* __restrict__ out)
{
    int row = blockIdx.x * 4 + (threadIdx.x >> 6);
    int lane = threadIdx.x & 63;
    const u16* rp = in + (size_t)row * DIM;
    u16x8 v0 = *(const u16x8*)(rp + lane * 8);
    u16x8 v1 = *(const u16x8*)(rp + 512 + lane * 8);
    float f[16];
    #pragma unroll
    for (int j = 0; j < 8; ++j) { f[j] = h2f(v0[j]); f[8 + j] = h2f(v1[j]); }
    float s = 0.f, sq = 0.f;
    #pragma unroll
    for (int j = 0; j < 16; ++j) { s += f[j]; sq += f[j] * f[j]; }
    #pragma unroll
    for (int m = 1; m < 64; m <<= 1) { s += __shfl_xor(s, m); sq += __shfl_xor(sq, m); }
    float mean = s * (1.0f / 1024.0f);
    float var = sq * (1.0f / 1024.0f) - mean * mean;
    float rstd = 1.0f / sqrtf(var + 1e-5f);
    u16x8 o0, o1;
    #pragma unroll
    for (int j = 0; j < 8; ++j) {
        int c0 = lane * 8 + j, c1 = 512 + lane * 8 + j;
        o0[j] = f2h((f[j] - mean) * rstd * g[c0] + b[c0]);
        o1[j] = f2h((f[8 + j] - mean) * rstd * g[c1] + b[c1]);
    }
    u16* op = out + (size_t)row * DIM;
    *(u16x8*)(op + lane * 8) = o0;
    *(u16x8*)(op + 512 + lane * 8) = o1;
}

extern "C" void kernel_launch(void* const* d_in, const int* in_sizes, int n_in,
                              void* d_out, int out_size, void* d_ws, size_t ws_size,
                              hipStream_t stream) {
    const float* x      = (const float*)d_in[0];
    const int*   wq     = (const int*)d_in[1];
    const float* scales = (const float*)d_in[2];
    const float* bias   = (const float*)d_in[3];
    const float* la     = (const float*)d_in[4];
    const float* lb     = (const float*)d_in[5];
    const float* gamma  = (const float*)d_in[6];
    const float* beta   = (const float*)d_in[7];

    char* ws = (char*)d_ws;
    u16* Weff = (u16*)ws;                                      // 37,748,736 B
    u16* actA = (u16*)(ws + (size_t)NLIN * DIM * DIM * 2);     // 67,108,864 B
    u16* actB = actA + (size_t)BATCH * DIM;                    // 67,108,864 B
    u16* dob  = (u16*)d_out;   // d_out doubles as fp16 scratch (134 MB total)
    float* dof = (float*)d_out;

    build_weff<<<dim3(64, 18), 256, 0, stream>>>(wq, scales, la, lb, Weff);
    xcast<<<(BATCH * DIM) / 2048, 256, 0, stream>>>(x, actA);

    int li = 0;
    for (int blk = 0; blk < 6; ++blk) {
        const u16* w0 = Weff + (size_t)(li + 0) * DIM * DIM;
        const u16* w1 = Weff + (size_t)(li + 1) * DIM * DIM;
        const u16* w2 = Weff + (size_t)(li + 2) * DIM * DIM;
        const float* b0 = bias + (li + 0) * DIM;
        const float* b1 = bias + (li + 1) * DIM;
        const float* b2 = bias + (li + 2) * DIM;
        if (blk < 5) {
            // X(actA) -> h1(actB) -> h2(d_out fp16) -> h3(actB) -> LN -> actA
            gemm256<0><<<512, 512, 0, stream>>>(actA, w0, b0, nullptr, actB);
            gemm256<0><<<512, 512, 0, stream>>>(actB, w1, b1, nullptr, dob);
            gemm256<1><<<512, 512, 0, stream>>>(dob,  w2, b2, actA, actB);
            ln_k<<<BATCH / 4, 256, 0, stream>>>(actB, gamma + blk * DIM, beta + blk * DIM, actA);
        } else {
            // final block: keep d_out free of live reads at the fp32 write
            gemm256<0><<<512, 512, 0, stream>>>(actA, w0, b0, nullptr, dob);
            gemm256<0><<<512, 512, 0, stream>>>(dob,  w1, b1, nullptr, actB);
            gemm256<2><<<512, 512, 0, stream>>>(actB, w2, b2, actA, (void*)dof);
        }
        li += 3;
    }
}

// Round 12
// 1469.183 us; speedup vs baseline: 1.0713x; 1.0190x over previous
//
#include <hip/hip_runtime.h>

typedef unsigned int u32;
typedef unsigned short u16;
typedef _Float16 f16;
typedef f16 f16x8 __attribute__((ext_vector_type(8)));
typedef float f32x4 __attribute__((ext_vector_type(4)));
typedef u16 u16x8 __attribute__((ext_vector_type(8)));

#define DIM 1024
#define BATCH 32768
#define RANK 32
#define NLIN 18

__device__ __forceinline__ u16 f2h(float f) {
    f16 h = (f16)f;
    return *(u16*)&h;
}
__device__ __forceinline__ float h2f(u16 u) {
    f16 h;
    *(u16*)&h = u;
    return (float)h;
}

__device__ __forceinline__ void gload16(const u16* g, u16* l) {
    __builtin_amdgcn_global_load_lds((__attribute__((address_space(1))) const void*)g,
                                     (__attribute__((address_space(3))) void*)l,
                                     16, 0, 0);
}

#define BAR()        __builtin_amdgcn_s_barrier()
#define SB0()        __builtin_amdgcn_sched_barrier(0)
#define ASM_VM0()    asm volatile("s_waitcnt vmcnt(0)" ::: "memory")
#define ASM_VM4()    asm volatile("s_waitcnt vmcnt(4)" ::: "memory")
#define ASM_VM8()    asm volatile("s_waitcnt vmcnt(8)" ::: "memory")
#define ASM_LG0()    asm volatile("s_waitcnt lgkmcnt(0)" ::: "memory")
#define ASM_LG4()    asm volatile("s_waitcnt lgkmcnt(4)" ::: "memory")

// ---- W_eff = dequant(wq, scales) + lb @ la  -> fp16 [NLIN][DIM][DIM] ----
__global__ __launch_bounds__(256) void build_weff(
    const int* __restrict__ wq, const float* __restrict__ scales,
    const float* __restrict__ la, const float* __restrict__ lb,
    u16* __restrict__ weff)
{
    const int rb = blockIdx.x;   // 0..63, 16 rows each
    const int li = blockIdx.y;   // 0..17
    const int tid = threadIdx.x;
    const int row0 = rb * 16;
    const int* wqL = wq + (size_t)li * DIM * DIM;
    const float* sL = scales + (size_t)li * (DIM * DIM / 16);
    const float* laL = la + (size_t)li * RANK * DIM;
    const float* lbL = lb + (size_t)li * DIM * RANK;
    u16* wout = weff + (size_t)li * DIM * DIM;

    for (int kc = 0; kc < 4; ++kc) {
        const int k = kc * 256 + tid;
        float lar[RANK];
        #pragma unroll
        for (int r = 0; r < RANK; ++r) lar[r] = laL[r * DIM + k];
        const int ks = k >> 4;
        #pragma unroll
        for (int og = 0; og < 16; og += 4) {
            const int m0 = row0 + og;
            float a0 = ((float)wqL[(m0 + 0) * DIM + k] - 8.0f) * sL[((m0 + 0) << 6) + ks];
            float a1 = ((float)wqL[(m0 + 1) * DIM + k] - 8.0f) * sL[((m0 + 1) << 6) + ks];
            float a2 = ((float)wqL[(m0 + 2) * DIM + k] - 8.0f) * sL[((m0 + 2) << 6) + ks];
            float a3 = ((float)wqL[(m0 + 3) * DIM + k] - 8.0f) * sL[((m0 + 3) << 6) + ks];
            #pragma unroll
            for (int r = 0; r < RANK; ++r) {
                const float lv = lar[r];
                a0 += lbL[(m0 + 0) * RANK + r] * lv;
                a1 += lbL[(m0 + 1) * RANK + r] * lv;
                a2 += lbL[(m0 + 2) * RANK + r] * lv;
                a3 += lbL[(m0 + 3) * RANK + r] * lv;
            }
            wout[(m0 + 0) * DIM + k] = f2h(a0);
            wout[(m0 + 1) * DIM + k] = f2h(a1);
            wout[(m0 + 2) * DIM + k] = f2h(a2);
            wout[(m0 + 3) * DIM + k] = f2h(a3);
        }
    }
}

// ---- x fp32 -> fp16 ----
__global__ __launch_bounds__(256) void xcast(const float* __restrict__ x, u16* __restrict__ o) {
    size_t i = ((size_t)blockIdx.x * 256 + threadIdx.x) * 8;
    float4 a = *(const float4*)(x + i);
    float4 b = *(const float4*)(x + i + 4);
    u16x8 v;
    v[0] = f2h(a.x); v[1] = f2h(a.y); v[2] = f2h(a.z); v[3] = f2h(a.w);
    v[4] = f2h(b.x); v[5] = f2h(b.y); v[6] = f2h(b.z); v[7] = f2h(b.w);
    *(u16x8*)(o + i) = v;
}

// ---- 256x256x(BK=64) GEMM, 8 waves (2Mx4N), 4 single-barrier phases/K-tile.
// Burst-split: r8 drained 24 ds_reads at one lgkmcnt(0) (192-instr CU backlog
// = the stall). Here each phase drains <=8: bf halves read EARLY (phase-top,
// full-phase cover; WAR-safe: bf01 overwritten 1 phase after last use), af
// halves post-QUAD (single-set reg constraint). Counted lgkm per phase.
// Staging regions (race-free, r8-proven): A 3-buf staged @ph0 (region >=2
// barriers past last reader drain), B 2-buf @ph3. Single VM4 @ph2 certifies
// tile t+1 before the ph3 early-reads (FIFO: leaves A(t+2) in flight).
// LDS = 96K A + 64K B = 160 KiB. Zero-conflict chunk-XOR swizzle.
// EPI: 0 = relu(acc+bias)->fp16 ; 1 = acc+bias+res->fp16 ; 2 = acc+bias+res->fp32
template<int EPI>
__global__ __launch_bounds__(512, 2) void gemm256(
    const u16* __restrict__ X, const u16* __restrict__ W,
    const float* __restrict__ bias, const u16* __restrict__ res,
    void* __restrict__ outp)
{
    __shared__ __align__(16) u16 As3[3 * 16384];
    __shared__ __align__(16) u16 Bs[2 * 16384];
    const int tid = threadIdx.x;
    const int bid = blockIdx.x;
    // XCD-bijective swizzle: 512 blocks, 8 XCDs, 64 contiguous wg per XCD
    const int wg = (bid & 7) * 64 + (bid >> 3);
    const int bm = wg >> 2;        // 0..127
    const int bn = wg & 3;         // 0..3
    const int wid = tid >> 6;
    const int lane = tid & 63;
    const int wm = wid >> 2;       // 0..1
    const int wn = wid & 3;        // 0..3

    // ---- staging source pointers (global side carries the swizzle) ----
    const int c1 = tid, c2 = tid + 512;           // chunk ids within a 1024-chunk half
    const int r1 = c1 >> 3, r2 = c2 >> 3;         // rows 0..127 within half
    const int l1 = ((c1 & 7) ^ (r1 & 7)) * 8;     // swizzled k-offset (u16)
    const int l2 = ((c2 & 7) ^ (r2 & 7)) * 8;
    const u16* gA0a = X + (size_t)(bm * 256 +       r1) * DIM + l1;
    const u16* gA0b = X + (size_t)(bm * 256 +       r2) * DIM + l2;
    const u16* gA1a = X + (size_t)(bm * 256 + 128 + r1) * DIM + l1;
    const u16* gA1b = X + (size_t)(bm * 256 + 128 + r2) * DIM + l2;
    const u16* gB0a = W + (size_t)(bn * 256 +       r1) * DIM + l1;
    const u16* gB0b = W + (size_t)(bn * 256 +       r2) * DIM + l2;
    const u16* gB1a = W + (size_t)(bn * 256 + 128 + r1) * DIM + l1;
    const u16* gB1b = W + (size_t)(bn * 256 + 128 + r2) * DIM + l2;
    const int d1 = c1 * 8, d2 = c2 * 8;           // linear LDS dest (u16), half adds 8192

    // ---- fragment read offsets ----
    const int kg = lane >> 4;
    const int sw = lane & 7;
    const int ch0 = ((0 * 4 + kg) ^ sw) * 8;      // ks=0 chunk (u16 offset in row)
    const int ch1 = ((1 * 4 + kg) ^ sw) * 8;      // ks=1
    const int aoff = (wm * 128 + (lane & 15)) * 64;
    const int boff = (wn * 64 + (lane & 15)) * 64;

    f32x4 acc[8][4];
    #pragma unroll
    for (int i = 0; i < 8; ++i)
        #pragma unroll
        for (int j = 0; j < 4; ++j)
            acc[i][j] = (f32x4){0.f, 0.f, 0.f, 0.f};
    f16x8 af[4][2];   // A fragments (one half at a time)
    f16x8 bf[4][2];   // B fragments (bf[0:1]=cols 0-31, bf[2:3]=cols 32-63)

    #define RD_A(MH, BUF) { \
        _Pragma("unroll") \
        for (int fm = 0; fm < 4; ++fm) { \
            af[fm][0] = *(const f16x8*)&(BUF)[aoff + ((MH)*64 + fm*16)*64 + ch0]; \
            af[fm][1] = *(const f16x8*)&(BUF)[aoff + ((MH)*64 + fm*16)*64 + ch1]; \
        } }
    #define RD_B01(BUF) { \
        _Pragma("unroll") \
        for (int fn = 0; fn < 2; ++fn) { \
            bf[fn][0] = *(const f16x8*)&(BUF)[boff + (fn*16)*64 + ch0]; \
            bf[fn][1] = *(const f16x8*)&(BUF)[boff + (fn*16)*64 + ch1]; \
        } }
    #define RD_B23(BUF) { \
        _Pragma("unroll") \
        for (int fn = 2; fn < 4; ++fn) { \
            bf[fn][0] = *(const f16x8*)&(BUF)[boff + (fn*16)*64 + ch0]; \
            bf[fn][1] = *(const f16x8*)&(BUF)[boff + (fn*16)*64 + ch1]; \
        } }
    #define QUAD(MH, NH) { \
        __builtin_amdgcn_s_setprio(1); \
        _Pragma("unroll") \
        for (int ks = 0; ks < 2; ++ks) \
            _Pragma("unroll") \
            for (int fm = 0; fm < 4; ++fm) \
                _Pragma("unroll") \
                for (int fn = 0; fn < 2; ++fn) \
                    acc[(MH)*4+fm][(NH)*2+fn] = __builtin_amdgcn_mfma_f32_16x16x32_f16( \
                        af[fm][ks], bf[(NH)*2+fn][ks], acc[(MH)*4+fm][(NH)*2+fn], 0, 0, 0); \
        __builtin_amdgcn_s_setprio(0); }

    // ---- prologue: stage A(0),B(0),A(1),B(1) — FIFO order matters ----
    gload16(gA0a, &As3[d1]);        gload16(gA0b, &As3[d2]);
    gload16(gA1a, &As3[8192 + d1]); gload16(gA1b, &As3[8192 + d2]);
    gload16(gB0a, &Bs[d1]);         gload16(gB0b, &Bs[d2]);
    gload16(gB1a, &Bs[8192 + d1]);  gload16(gB1b, &Bs[8192 + d2]);
    gload16(gA0a + 64, &As3[16384 + d1]);        gload16(gA0b + 64, &As3[16384 + d2]);
    gload16(gA1a + 64, &As3[16384 + 8192 + d1]); gload16(gA1b + 64, &As3[16384 + 8192 + d2]);
    gload16(gB0a + 64, &Bs[16384 + d1]);         gload16(gB0b + 64, &Bs[16384 + d2]);
    gload16(gB1a + 64, &Bs[16384 + 8192 + d1]);  gload16(gB1b + 64, &Bs[16384 + 8192 + d2]);

    ASM_VM8();     // A(0),B(0) landed (A(1),B(1) stay in flight)
    BAR();
    // emulate ph3(-1): afh0(0) + bf01(0)
    RD_A(0, (&As3[0]));
    RD_B01((&Bs[0]));
    SB0();

    int aCur = 0, aNext = 16384, aWr = 32768;
    #pragma unroll 1
    for (int t = 0; t < 16; ++t) {
        const int ko2 = (t + 2) * 64;
        const bool st = (t <= 13);
        const int bCur = (t & 1) ? 16384 : 0;
        const int bNext = bCur ^ 16384;
        // ---- ph0: QUAD(0,0) [afh0(t) x bf01(t)] ----
        RD_B23((&Bs[bCur]));                       // early: consumed ph1
        if (st) { gload16(gA0a + ko2, &As3[aWr + d1]); gload16(gA0b + ko2, &As3[aWr + d2]);
                  gload16(gA1a + ko2, &As3[aWr + 8192 + d1]); gload16(gA1b + ko2, &As3[aWr + 8192 + d2]); }
        SB0();
        BAR();
        ASM_LG4(); SB0();                          // afh0+bf01 done; bf23 in flight
        QUAD(0, 0);
        // ---- ph1: QUAD(0,1) [afh0 x bf23] ----
        BAR();
        ASM_LG0(); SB0();                          // bf23 done
        QUAD(0, 1);
        RD_A(1, (&As3[aCur]));                     // afh1(t), AFTER its h0-consumers
        SB0();
        // ---- ph2: QUAD(1,0) [afh1 x bf01] ----
        if (st) ASM_VM4(); else if (t == 14) ASM_VM0();   // certify tile t+1 staging
        BAR();
        ASM_LG0(); SB0();                          // afh1 done
        QUAD(1, 0);
        // ---- ph3: QUAD(1,1) [afh1 x bf23] ----
        if (t <= 14) RD_B01((&Bs[bNext]));         // early: bf01(t+1); WAR-safe (last use ph2)
        if (st) { gload16(gB0a + ko2, &Bs[bCur + d1]); gload16(gB0b + ko2, &Bs[bCur + d2]);
                  gload16(gB1a + ko2, &Bs[bCur + 8192 + d1]); gload16(gB1b + ko2, &Bs[bCur + 8192 + d2]); }
        SB0();
        BAR();
        SB0();
        QUAD(1, 1);                                // operands already in regs; no LG
        if (t <= 14) RD_A(0, (&As3[aNext]));       // afh0(t+1), AFTER its h... consumers
        SB0();
        int tmp = aCur; aCur = aNext; aNext = aWr; aWr = tmp;
    }

    // ---- epilogue: LDS transpose -> full-line vector stores (r8-proven) ----
    ASM_LG0();
    float* blk = (float*)&As3[0] + wid * 1088;   // [16][68] f32 per wave
    const int mrow = bm * 256 + wm * 128;
    const int ncol = bn * 256 + wn * 64 + (lane & 7) * 8;
    float4 bv0 = *(const float4*)&bias[ncol];
    float4 bv1 = *(const float4*)&bias[ncol + 4];
    #pragma unroll
    for (int fm = 0; fm < 8; ++fm) {
        __builtin_amdgcn_sched_barrier(0);
        #pragma unroll
        for (int fn = 0; fn < 4; ++fn)
            #pragma unroll
            for (int reg = 0; reg < 4; ++reg)
                blk[((lane >> 4) * 4 + reg) * 68 + (lane & 15) + fn * 16] = acc[fm][fn][reg];
        ASM_LG0();
        __builtin_amdgcn_sched_barrier(0);
        #pragma unroll
        for (int pass = 0; pass < 2; ++pass) {
            const float* rp = &blk[(pass * 8 + (lane >> 3)) * 68 + (lane & 7) * 8];
            float4 v0 = *(const float4*)rp;
            float4 v1 = *(const float4*)(rp + 4);
            v0.x += bv0.x; v0.y += bv0.y; v0.z += bv0.z; v0.w += bv0.w;
            v1.x += bv1.x; v1.y += bv1.y; v1.z += bv1.z; v1.w += bv1.w;
            const int m = mrow + fm * 16 + pass * 8 + (lane >> 3);
            const size_t gi = (size_t)m * DIM + ncol;
            if (EPI == 0) {
                u16x8 o;
                o[0] = f2h(fmaxf(v0.x, 0.f)); o[1] = f2h(fmaxf(v0.y, 0.f));
                o[2] = f2h(fmaxf(v0.z, 0.f)); o[3] = f2h(fmaxf(v0.w, 0.f));
                o[4] = f2h(fmaxf(v1.x, 0.f)); o[5] = f2h(fmaxf(v1.y, 0.f));
                o[6] = f2h(fmaxf(v1.z, 0.f)); o[7] = f2h(fmaxf(v1.w, 0.f));
                *(u16x8*)((u16*)outp + gi) = o;
            } else {
                u16x8 rv = *(const u16x8*)(res + gi);
                v0.x += h2f(rv[0]); v0.y += h2f(rv[1]); v0.z += h2f(rv[2]); v0.w += h2f(rv[3]);
                v1.x += h2f(rv[4]); v1.y += h2f(rv[5]); v1.z += h2f(rv[6]); v1.w += h2f(rv[7]);
                if (EPI == 1) {
                    u16x8 o;
                    o[0] = f2h(v0.x); o[1] = f2h(v0.y); o[2] = f2h(v0.z); o[3] = f2h(v0.w);
                    o[4] = f2h(v1.x); o[5] = f2h(v1.y); o[6] = f2h(v1.z); o[7] = f2h(v1.w);
                    *(u16x8*)((u16*)outp + gi) = o;
                } else {
                    *(float4*)((float*)outp + gi) = v0;
                    *(float4*)((float*)outp + gi + 4) = v1;
                }
            }
        }
        ASM_LG0();
    }
    #undef RD_A
    #undef RD_B01
    #undef RD_B23
    #undef QUAD
}

// ---- LayerNorm: fp16 in -> fp16 out, one wave per row ----
__global__ __launch_bounds__(256) void ln_k(const u16* __restrict__ in,
    const float* __restrict__ g, const float* __restrict__ b, u16* __restrict__ out)
{
    int row = blockIdx.x * 4 + (threadIdx.x >> 6);
    int lane = threadIdx.x & 63;
    const u16* rp = in + (size_t)row * DIM;
    u16x8 v0 = *(const u16x8*)(rp + lane * 8);
    u16x8 v1 = *(const u16x8*)(rp + 512 + lane * 8);
    float f[16];
    #pragma unroll
    for (int j = 0; j < 8; ++j) { f[j] = h2f(v0[j]); f[8 + j] = h2f(v1[j]); }
    float s = 0.f, sq = 0.f;
    #pragma unroll
    for (int j = 0; j < 16; ++j) { s += f[j]; sq += f[j] * f[j]; }
    #pragma unroll
    for (int m = 1; m < 64; m <<= 1) { s += __shfl_xor(s, m); sq += __shfl_xor(sq, m); }
    float mean = s * (1.0f / 1024.0f);
    float var = sq * (1.0f / 1024.0f) - mean * mean;
    float rstd = 1.0f / sqrtf(var + 1e-5f);
    u16x8 o0, o1;
    #pragma unroll
    for (int j = 0; j < 8; ++j) {
        int c0 = lane * 8 + j, c1 = 512 + lane * 8 + j;
        o0[j] = f2h((f[j] - mean) * rstd * g[c0] + b[c0]);
        o1[j] = f2h((f[8 + j] - mean) * rstd * g[c1] + b[c1]);
    }
    u16* op = out + (size_t)row * DIM;
    *(u16x8*)(op + lane * 8) = o0;
    *(u16x8*)(op + 512 + lane * 8) = o1;
}

extern "C" void kernel_launch(void* const* d_in, const int* in_sizes, int n_in,
                              void* d_out, int out_size, void* d_ws, size_t ws_size,
                              hipStream_t stream) {
    const float* x      = (const float*)d_in[0];
    const int*   wq     = (const int*)d_in[1];
    const float* scales = (const float*)d_in[2];
    const float* bias   = (const float*)d_in[3];
    const float* la     = (const float*)d_in[4];
    const float* lb     = (const float*)d_in[5];
    const float* gamma  = (const float*)d_in[6];
    const float* beta   = (const float*)d_in[7];

    char* ws = (char*)d_ws;
    u16* Weff = (u16*)ws;                                      // 37,748,736 B
    u16* actA = (u16*)(ws + (size_t)NLIN * DIM * DIM * 2);     // 67,108,864 B
    u16* actB = actA + (size_t)BATCH * DIM;                    // 67,108,864 B
    u16* dob  = (u16*)d_out;   // d_out doubles as fp16 scratch (134 MB total)
    float* dof = (float*)d_out;

    build_weff<<<dim3(64, 18), 256, 0, stream>>>(wq, scales, la, lb, Weff);
    xcast<<<(BATCH * DIM) / 2048, 256, 0, stream>>>(x, actA);

    int li = 0;
    for (int blk = 0; blk < 6; ++blk) {
        const u16* w0 = Weff + (size_t)(li + 0) * DIM * DIM;
        const u16* w1 = Weff + (size_t)(li + 1) * DIM * DIM;
        const u16* w2 = Weff + (size_t)(li + 2) * DIM * DIM;
        const float* b0 = bias + (li + 0) * DIM;
        const float* b1 = bias + (li + 1) * DIM;
        const float* b2 = bias + (li + 2) * DIM;
        if (blk < 5) {
            // X(actA) -> h1(actB) -> h2(d_out fp16) -> h3(actB) -> LN -> actA
            gemm256<0><<<512, 512, 0, stream>>>(actA, w0, b0, nullptr, actB);
            gemm256<0><<<512, 512, 0, stream>>>(actB, w1, b1, nullptr, dob);
            gemm256<1><<<512, 512, 0, stream>>>(dob,  w2, b2, actA, actB);
            ln_k<<<BATCH / 4, 256, 0, stream>>>(actB, gamma + blk * DIM, beta + blk * DIM, actA);
        } else {
            // final block: keep d_out free of live reads at the fp32 write
            gemm256<0><<<512, 512, 0, stream>>>(actA, w0, b0, nullptr, dob);
            gemm256<0><<<512, 512, 0, stream>>>(dob,  w1, b1, nullptr, actB);
            gemm256<2><<<512, 512, 0, stream>>>(actB, w2, b2, actA, (void*)dof);
        }
        li += 3;
    }
}

// Round 13
// 1462.278 us; speedup vs baseline: 1.0763x; 1.0047x over previous
//
#include <hip/hip_runtime.h>

typedef unsigned int u32;
typedef unsigned short u16;
typedef _Float16 f16;
typedef f16 f16x8 __attribute__((ext_vector_type(8)));
typedef float f32x4 __attribute__((ext_vector_type(4)));
typedef u16 u16x8 __attribute__((ext_vector_type(8)));

#define DIM 1024
#define BATCH 32768
#define RANK 32
#define NLIN 18

__device__ __forceinline__ u16 f2h(float f) {
    f16 h = (f16)f;
    return *(u16*)&h;
}
__device__ __forceinline__ float h2f(u16 u) {
    f16 h;
    *(u16*)&h = u;
    return (float)h;
}

__device__ __forceinline__ void gload16(const u16* g, u16* l) {
    __builtin_amdgcn_global_load_lds((__attribute__((address_space(1))) const void*)g,
                                     (__attribute__((address_space(3))) void*)l,
                                     16, 0, 0);
}

#define BAR()        __builtin_amdgcn_s_barrier()
#define SB0()        __builtin_amdgcn_sched_barrier(0)
#define ASM_VM0()    asm volatile("s_waitcnt vmcnt(0)" ::: "memory")
#define ASM_VM4()    asm volatile("s_waitcnt vmcnt(4)" ::: "memory")
#define ASM_VM8()    asm volatile("s_waitcnt vmcnt(8)" ::: "memory")
#define ASM_LG0()    asm volatile("s_waitcnt lgkmcnt(0)" ::: "memory")
#define ASM_LG4()    asm volatile("s_waitcnt lgkmcnt(4)" ::: "memory")

// ---- W_eff = dequant(wq, scales) + lb @ la  -> fp16 [NLIN][DIM][DIM] ----
__global__ __launch_bounds__(256) void build_weff(
    const int* __restrict__ wq, const float* __restrict__ scales,
    const float* __restrict__ la, const float* __restrict__ lb,
    u16* __restrict__ weff)
{
    const int rb = blockIdx.x;   // 0..63, 16 rows each
    const int li = blockIdx.y;   // 0..17
    const int tid = threadIdx.x;
    const int row0 = rb * 16;
    const int* wqL = wq + (size_t)li * DIM * DIM;
    const float* sL = scales + (size_t)li * (DIM * DIM / 16);
    const float* laL = la + (size_t)li * RANK * DIM;
    const float* lbL = lb + (size_t)li * DIM * RANK;
    u16* wout = weff + (size_t)li * DIM * DIM;

    for (int kc = 0; kc < 4; ++kc) {
        const int k = kc * 256 + tid;
        float lar[RANK];
        #pragma unroll
        for (int r = 0; r < RANK; ++r) lar[r] = laL[r * DIM + k];
        const int ks = k >> 4;
        #pragma unroll
        for (int og = 0; og < 16; og += 4) {
            const int m0 = row0 + og;
            float a0 = ((float)wqL[(m0 + 0) * DIM + k] - 8.0f) * sL[((m0 + 0) << 6) + ks];
            float a1 = ((float)wqL[(m0 + 1) * DIM + k] - 8.0f) * sL[((m0 + 1) << 6) + ks];
            float a2 = ((float)wqL[(m0 + 2) * DIM + k] - 8.0f) * sL[((m0 + 2) << 6) + ks];
            float a3 = ((float)wqL[(m0 + 3) * DIM + k] - 8.0f) * sL[((m0 + 3) << 6) + ks];
            #pragma unroll
            for (int r = 0; r < RANK; ++r) {
                const float lv = lar[r];
                a0 += lbL[(m0 + 0) * RANK + r] * lv;
                a1 += lbL[(m0 + 1) * RANK + r] * lv;
                a2 += lbL[(m0 + 2) * RANK + r] * lv;
                a3 += lbL[(m0 + 3) * RANK + r] * lv;
            }
            wout[(m0 + 0) * DIM + k] = f2h(a0);
            wout[(m0 + 1) * DIM + k] = f2h(a1);
            wout[(m0 + 2) * DIM + k] = f2h(a2);
            wout[(m0 + 3) * DIM + k] = f2h(a3);
        }
    }
}

// ---- x fp32 -> fp16 ----
__global__ __launch_bounds__(256) void xcast(const float* __restrict__ x, u16* __restrict__ o) {
    size_t i = ((size_t)blockIdx.x * 256 + threadIdx.x) * 8;
    float4 a = *(const float4*)(x + i);
    float4 b = *(const float4*)(x + i + 4);
    u16x8 v;
    v[0] = f2h(a.x); v[1] = f2h(a.y); v[2] = f2h(a.z); v[3] = f2h(a.w);
    v[4] = f2h(b.x); v[5] = f2h(b.y); v[6] = f2h(b.z); v[7] = f2h(b.w);
    *(u16x8*)(o + i) = v;
}

// ---- 256x256x(BK=64) GEMM, 8 waves (2Mx4N), 4 single-barrier phases/K-tile
// (r12 loop, best-measured tie with r8). Race-free staging: A 3-buf @ph0,
// B 2-buf @ph3; single VM4 @ph2 certifies tile t+1. Zero-conflict chunk-XOR
// swizzle. NEW in r13: epilogue res-read is PIPELINED 2-deep across the fm
// loop (issue fm+1's loads before processing fm) — hides the ~450cy L3
// latency that made EPI1/EPI2 dispatches ~26us slower than EPI0.
// EPI: 0 = relu(acc+bias)->fp16 ; 1 = acc+bias+res->fp16 ; 2 = acc+bias+res->fp32
template<int EPI>
__global__ __launch_bounds__(512, 2) void gemm256(
    const u16* __restrict__ X, const u16* __restrict__ W,
    const float* __restrict__ bias, const u16* __restrict__ res,
    void* __restrict__ outp)
{
    __shared__ __align__(16) u16 As3[3 * 16384];
    __shared__ __align__(16) u16 Bs[2 * 16384];
    const int tid = threadIdx.x;
    const int bid = blockIdx.x;
    // XCD-bijective swizzle: 512 blocks, 8 XCDs, 64 contiguous wg per XCD
    const int wg = (bid & 7) * 64 + (bid >> 3);
    const int bm = wg >> 2;        // 0..127
    const int bn = wg & 3;         // 0..3
    const int wid = tid >> 6;
    const int lane = tid & 63;
    const int wm = wid >> 2;       // 0..1
    const int wn = wid & 3;        // 0..3

    // ---- staging source pointers (global side carries the swizzle) ----
    const int c1 = tid, c2 = tid + 512;           // chunk ids within a 1024-chunk half
    const int r1 = c1 >> 3, r2 = c2 >> 3;         // rows 0..127 within half
    const int l1 = ((c1 & 7) ^ (r1 & 7)) * 8;     // swizzled k-offset (u16)
    const int l2 = ((c2 & 7) ^ (r2 & 7)) * 8;
    const u16* gA0a = X + (size_t)(bm * 256 +       r1) * DIM + l1;
    const u16* gA0b = X + (size_t)(bm * 256 +       r2) * DIM + l2;
    const u16* gA1a = X + (size_t)(bm * 256 + 128 + r1) * DIM + l1;
    const u16* gA1b = X + (size_t)(bm * 256 + 128 + r2) * DIM + l2;
    const u16* gB0a = W + (size_t)(bn * 256 +       r1) * DIM + l1;
    const u16* gB0b = W + (size_t)(bn * 256 +       r2) * DIM + l2;
    const u16* gB1a = W + (size_t)(bn * 256 + 128 + r1) * DIM + l1;
    const u16* gB1b = W + (size_t)(bn * 256 + 128 + r2) * DIM + l2;
    const int d1 = c1 * 8, d2 = c2 * 8;           // linear LDS dest (u16), half adds 8192

    // ---- fragment read offsets ----
    const int kg = lane >> 4;
    const int sw = lane & 7;
    const int ch0 = ((0 * 4 + kg) ^ sw) * 8;      // ks=0 chunk (u16 offset in row)
    const int ch1 = ((1 * 4 + kg) ^ sw) * 8;      // ks=1
    const int aoff = (wm * 128 + (lane & 15)) * 64;
    const int boff = (wn * 64 + (lane & 15)) * 64;

    f32x4 acc[8][4];
    #pragma unroll
    for (int i = 0; i < 8; ++i)
        #pragma unroll
        for (int j = 0; j < 4; ++j)
            acc[i][j] = (f32x4){0.f, 0.f, 0.f, 0.f};
    f16x8 af[4][2];   // A fragments (one half at a time)
    f16x8 bf[4][2];   // B fragments (bf[0:1]=cols 0-31, bf[2:3]=cols 32-63)

    #define RD_A(MH, BUF) { \
        _Pragma("unroll") \
        for (int fm = 0; fm < 4; ++fm) { \
            af[fm][0] = *(const f16x8*)&(BUF)[aoff + ((MH)*64 + fm*16)*64 + ch0]; \
            af[fm][1] = *(const f16x8*)&(BUF)[aoff + ((MH)*64 + fm*16)*64 + ch1]; \
        } }
    #define RD_B01(BUF) { \
        _Pragma("unroll") \
        for (int fn = 0; fn < 2; ++fn) { \
            bf[fn][0] = *(const f16x8*)&(BUF)[boff + (fn*16)*64 + ch0]; \
            bf[fn][1] = *(const f16x8*)&(BUF)[boff + (fn*16)*64 + ch1]; \
        } }
    #define RD_B23(BUF) { \
        _Pragma("unroll") \
        for (int fn = 2; fn < 4; ++fn) { \
            bf[fn][0] = *(const f16x8*)&(BUF)[boff + (fn*16)*64 + ch0]; \
            bf[fn][1] = *(const f16x8*)&(BUF)[boff + (fn*16)*64 + ch1]; \
        } }
    #define QUAD(MH, NH) { \
        __builtin_amdgcn_s_setprio(1); \
        _Pragma("unroll") \
        for (int ks = 0; ks < 2; ++ks) \
            _Pragma("unroll") \
            for (int fm = 0; fm < 4; ++fm) \
                _Pragma("unroll") \
                for (int fn = 0; fn < 2; ++fn) \
                    acc[(MH)*4+fm][(NH)*2+fn] = __builtin_amdgcn_mfma_f32_16x16x32_f16( \
                        af[fm][ks], bf[(NH)*2+fn][ks], acc[(MH)*4+fm][(NH)*2+fn], 0, 0, 0); \
        __builtin_amdgcn_s_setprio(0); }

    // ---- prologue: stage A(0),B(0),A(1),B(1) — FIFO order matters ----
    gload16(gA0a, &As3[d1]);        gload16(gA0b, &As3[d2]);
    gload16(gA1a, &As3[8192 + d1]); gload16(gA1b, &As3[8192 + d2]);
    gload16(gB0a, &Bs[d1]);         gload16(gB0b, &Bs[d2]);
    gload16(gB1a, &Bs[8192 + d1]);  gload16(gB1b, &Bs[8192 + d2]);
    gload16(gA0a + 64, &As3[16384 + d1]);        gload16(gA0b + 64, &As3[16384 + d2]);
    gload16(gA1a + 64, &As3[16384 + 8192 + d1]); gload16(gA1b + 64, &As3[16384 + 8192 + d2]);
    gload16(gB0a + 64, &Bs[16384 + d1]);         gload16(gB0b + 64, &Bs[16384 + d2]);
    gload16(gB1a + 64, &Bs[16384 + 8192 + d1]);  gload16(gB1b + 64, &Bs[16384 + 8192 + d2]);

    ASM_VM8();     // A(0),B(0) landed (A(1),B(1) stay in flight)
    BAR();
    // emulate ph3(-1): afh0(0) + bf01(0)
    RD_A(0, (&As3[0]));
    RD_B01((&Bs[0]));
    SB0();

    int aCur = 0, aNext = 16384, aWr = 32768;
    #pragma unroll 1
    for (int t = 0; t < 16; ++t) {
        const int ko2 = (t + 2) * 64;
        const bool st = (t <= 13);
        const int bCur = (t & 1) ? 16384 : 0;
        const int bNext = bCur ^ 16384;
        // ---- ph0: QUAD(0,0) [afh0(t) x bf01(t)] ----
        RD_B23((&Bs[bCur]));                       // early: consumed ph1
        if (st) { gload16(gA0a + ko2, &As3[aWr + d1]); gload16(gA0b + ko2, &As3[aWr + d2]);
                  gload16(gA1a + ko2, &As3[aWr + 8192 + d1]); gload16(gA1b + ko2, &As3[aWr + 8192 + d2]); }
        SB0();
        BAR();
        ASM_LG4(); SB0();                          // afh0+bf01 done; bf23 in flight
        QUAD(0, 0);
        // ---- ph1: QUAD(0,1) [afh0 x bf23] ----
        BAR();
        ASM_LG0(); SB0();                          // bf23 done
        QUAD(0, 1);
        RD_A(1, (&As3[aCur]));                     // afh1(t), AFTER its h0-consumers
        SB0();
        // ---- ph2: QUAD(1,0) [afh1 x bf01] ----
        if (st) ASM_VM4(); else if (t == 14) ASM_VM0();   // certify tile t+1 staging
        BAR();
        ASM_LG0(); SB0();                          // afh1 done
        QUAD(1, 0);
        // ---- ph3: QUAD(1,1) [afh1 x bf23] ----
        if (t <= 14) RD_B01((&Bs[bNext]));         // early: bf01(t+1); WAR-safe (last use ph2)
        if (st) { gload16(gB0a + ko2, &Bs[bCur + d1]); gload16(gB0b + ko2, &Bs[bCur + d2]);
                  gload16(gB1a + ko2, &Bs[bCur + 8192 + d1]); gload16(gB1b + ko2, &Bs[bCur + 8192 + d2]); }
        SB0();
        BAR();
        SB0();
        QUAD(1, 1);                                // operands already in regs; no LG
        if (t <= 14) RD_A(0, (&As3[aNext]));       // afh0(t+1), AFTER its consumers
        SB0();
        int tmp = aCur; aCur = aNext; aNext = aWr; aWr = tmp;
    }

    // ---- epilogue: LDS transpose -> full-line stores; res PIPELINED 2-deep ----
    ASM_LG0();
    float* blk = (float*)&As3[0] + wid * 1088;   // [16][68] f32 per wave
    const int mrow = bm * 256 + wm * 128;
    const int ncol = bn * 256 + wn * 64 + (lane & 7) * 8;
    float4 bv0 = *(const float4*)&bias[ncol];
    float4 bv1 = *(const float4*)&bias[ncol + 4];
    u16x8 rvp[2][2];   // res prefetch [parity][pass]
    if (EPI != 0) {
        #pragma unroll
        for (int pass = 0; pass < 2; ++pass) {
            const int m = mrow + pass * 8 + (lane >> 3);
            rvp[0][pass] = *(const u16x8*)(res + (size_t)m * DIM + ncol);
        }
    }
    #pragma unroll
    for (int fm = 0; fm < 8; ++fm) {
        if (EPI != 0 && fm < 7) {   // issue fm+1's res loads (consumed next iter)
            #pragma unroll
            for (int pass = 0; pass < 2; ++pass) {
                const int m = mrow + (fm + 1) * 16 + pass * 8 + (lane >> 3);
                rvp[(fm + 1) & 1][pass] = *(const u16x8*)(res + (size_t)m * DIM + ncol);
            }
        }
        __builtin_amdgcn_sched_barrier(0);
        #pragma unroll
        for (int fn = 0; fn < 4; ++fn)
            #pragma unroll
            for (int reg = 0; reg < 4; ++reg)
                blk[((lane >> 4) * 4 + reg) * 68 + (lane & 15) + fn * 16] = acc[fm][fn][reg];
        ASM_LG0();
        __builtin_amdgcn_sched_barrier(0);
        #pragma unroll
        for (int pass = 0; pass < 2; ++pass) {
            const float* rp = &blk[(pass * 8 + (lane >> 3)) * 68 + (lane & 7) * 8];
            float4 v0 = *(const float4*)rp;
            float4 v1 = *(const float4*)(rp + 4);
            v0.x += bv0.x; v0.y += bv0.y; v0.z += bv0.z; v0.w += bv0.w;
            v1.x += bv1.x; v1.y += bv1.y; v1.z += bv1.z; v1.w += bv1.w;
            const int m = mrow + fm * 16 + pass * 8 + (lane >> 3);
            const size_t gi = (size_t)m * DIM + ncol;
            if (EPI == 0) {
                u16x8 o;
                o[0] = f2h(fmaxf(v0.x, 0.f)); o[1] = f2h(fmaxf(v0.y, 0.f));
                o[2] = f2h(fmaxf(v0.z, 0.f)); o[3] = f2h(fmaxf(v0.w, 0.f));
                o[4] = f2h(fmaxf(v1.x, 0.f)); o[5] = f2h(fmaxf(v1.y, 0.f));
                o[6] = f2h(fmaxf(v1.z, 0.f)); o[7] = f2h(fmaxf(v1.w, 0.f));
                *(u16x8*)((u16*)outp + gi) = o;
            } else {
                u16x8 rv = rvp[fm & 1][pass];
                v0.x += h2f(rv[0]); v0.y += h2f(rv[1]); v0.z += h2f(rv[2]); v0.w += h2f(rv[3]);
                v1.x += h2f(rv[4]); v1.y += h2f(rv[5]); v1.z += h2f(rv[6]); v1.w += h2f(rv[7]);
                if (EPI == 1) {
                    u16x8 o;
                    o[0] = f2h(v0.x); o[1] = f2h(v0.y); o[2] = f2h(v0.z); o[3] = f2h(v0.w);
                    o[4] = f2h(v1.x); o[5] = f2h(v1.y); o[6] = f2h(v1.z); o[7] = f2h(v1.w);
                    *(u16x8*)((u16*)outp + gi) = o;
                } else {
                    *(float4*)((float*)outp + gi) = v0;
                    *(float4*)((float*)outp + gi + 4) = v1;
                }
            }
        }
        ASM_LG0();
    }
    #undef RD_A
    #undef RD_B01
    #undef RD_B23
    #undef QUAD
}

// ---- LayerNorm: fp16 in -> fp16 out, one wave per row ----
__global__ __launch_bounds__(256) void ln_k(const u16* __restrict__ in,
    const float* __restrict__ g, const float* __restrict__ b, u16* __restrict__ out)
{
    int row = blockIdx.x * 4 + (threadIdx.x >> 6);
    int lane = threadIdx.x & 63;
    const u16* rp = in + (size_t)row * DIM;
    u16x8 v0 = *(const u16x8*)(rp + lane * 8);
    u16x8 v1 = *(const u16x8*)(rp + 512 + lane * 8);
    float f[16];
    #pragma unroll
    for (int j = 0; j < 8; ++j) { f[j] = h2f(v0[j]); f[8 + j] = h2f(v1[j]); }
    float s = 0.f, sq = 0.f;
    #pragma unroll
    for (int j = 0; j < 16; ++j) { s += f[j]; sq += f[j] * f[j]; }
    #pragma unroll
    for (int m = 1; m < 64; m <<= 1) { s += __shfl_xor(s, m); sq += __shfl_xor(sq, m); }
    float mean = s * (1.0f / 1024.0f);
    float var = sq * (1.0f / 1024.0f) - mean * mean;
    float rstd = 1.0f / sqrtf(var + 1e-5f);
    u16x8 o0, o1;
    #pragma unroll
    for (int j = 0; j < 8; ++j) {
        int c0 = lane * 8 + j, c1 = 512 + lane * 8 + j;
        o0[j] = f2h((f[j] - mean) * rstd * g[c0] + b[c0]);
        o1[j] = f2h((f[8 + j] - mean) * rstd * g[c1] + b[c1]);
    }
    u16* op = out + (size_t)row * DIM;
    *(u16x8*)(op + lane * 8) = o0;
    *(u16x8*)(op + 512 + lane * 8) = o1;
}

extern "C" void kernel_launch(void* const* d_in, const int* in_sizes, int n_in,
                              void* d_out, int out_size, void* d_ws, size_t ws_size,
                              hipStream_t stream) {
    const float* x      = (const float*)d_in[0];
    const int*   wq     = (const int*)d_in[1];
    const float* scales = (const float*)d_in[2];
    const float* bias   = (const float*)d_in[3];
    const float* la     = (const float*)d_in[4];
    const float* lb     = (const float*)d_in[5];
    const float* gamma  = (const float*)d_in[6];
    const float* beta   = (const float*)d_in[7];

    char* ws = (char*)d_ws;
    u16* Weff = (u16*)ws;                                      // 37,748,736 B
    u16* actA = (u16*)(ws + (size_t)NLIN * DIM * DIM * 2);     // 67,108,864 B
    u16* actB = actA + (size_t)BATCH * DIM;                    // 67,108,864 B
    u16* dob  = (u16*)d_out;   // d_out doubles as fp16 scratch (134 MB total)
    float* dof = (float*)d_out;

    build_weff<<<dim3(64, 18), 256, 0, stream>>>(wq, scales, la, lb, Weff);
    xcast<<<(BATCH * DIM) / 2048, 256, 0, stream>>>(x, actA);

    int li = 0;
    for (int blk = 0; blk < 6; ++blk) {
        const u16* w0 = Weff + (size_t)(li + 0) * DIM * DIM;
        const u16* w1 = Weff + (size_t)(li + 1) * DIM * DIM;
        const u16* w2 = Weff + (size_t)(li + 2) * DIM * DIM;
        const float* b0 = bias + (li + 0) * DIM;
        const float* b1 = bias + (li + 1) * DIM;
        const float* b2 = bias + (li + 2) * DIM;
        if (blk < 5) {
            // X(actA) -> h1(actB) -> h2(d_out fp16) -> h3(actB) -> LN -> actA
            gemm256<0><<<512, 512, 0, stream>>>(actA, w0, b0, nullptr, actB);
            gemm256<0><<<512, 512, 0, stream>>>(actB, w1, b1, nullptr, dob);
            gemm256<1><<<512, 512, 0, stream>>>(dob,  w2, b2, actA, actB);
            ln_k<<<BATCH / 4, 256, 0, stream>>>(actB, gamma + blk * DIM, beta + blk * DIM, actA);
        } else {
            // final block: keep d_out free of live reads at the fp32 write
            gemm256<0><<<512, 512, 0, stream>>>(actA, w0, b0, nullptr, dob);
            gemm256<0><<<512, 512, 0, stream>>>(dob,  w1, b1, nullptr, actB);
            gemm256<2><<<512, 512, 0, stream>>>(actB, w2, b2, actA, (void*)dof);
        }
        li += 3;
    }
}